// Round 20
// baseline (213.069 us; speedup 1.0000x reference)
//
#include <hip/hip_runtime.h>

// ConvCapsMatrix EM routing, MI355X. Inputs FP32, output FP32.
// R20: (pos-pair, n-quarter) blocks: 512 thr = 2 pos x (8 ng x 32 o), 72 n's
// per block, j=9 -> 1152 blocks = 4 blocks/CU FULL 32-wave residency (R18's
// win) AND 2-way W-sharing inside each block + same-quarter co-residency via
// bid = pair*4 + quarter (blocks on one CU differ by 256 ≡ 0 mod 4 -> same
// quarter -> shared 16KB W j-slice in L1; W was thrashing the 32KB L1).
// Per-thread state recompute from global partials (no barriers). DPP softmax.
// Launches: S0 -> S1 -> S2 -> F; partials (pos,quarter) double-buffered in ws.

#define EPSV 1e-8f

template <int CTRL>
__device__ __forceinline__ float dppf(float v) {
  return __int_as_float(__builtin_amdgcn_update_dpp(
      0, __float_as_int(v), CTRL, 0xf, 0xf, true));
}
__device__ __forceinline__ float swz16(float v) {   // lane ^ 16 within 32-groups
  return __int_as_float(__builtin_amdgcn_ds_swizzle(__float_as_int(v), 0x401F));
}
__device__ __forceinline__ float red_max32(float v) {
  v = fmaxf(v, dppf<0xB1>(v));
  v = fmaxf(v, dppf<0x4E>(v));
  v = fmaxf(v, dppf<0x141>(v));
  v = fmaxf(v, dppf<0x140>(v));
  v = fmaxf(v, swz16(v));
  return v;
}
__device__ __forceinline__ float red_sum32(float v) {
  v += dppf<0xB1>(v);
  v += dppf<0x4E>(v);
  v += dppf<0x141>(v);
  v += dppf<0x140>(v);
  v += swz16(v);
  return v;
}

__device__ __forceinline__ void compute_votes(const float* __restrict__ Wt,
                                              const float* __restrict__ xr,
                                              int n, int o, float* __restrict__ V)
{
  // W[k,l,c,o,y,z] flat = (n*32+o)*16 + y*4+z ; xr = local pose row (16 f)
  float Wf[16];
  {
    const float* wp = Wt + (((n << 5) + o) << 4);
#pragma unroll
    for (int i = 0; i < 4; ++i) {
      const float4 q = *(const float4*)(wp + (i << 2));
      Wf[i*4+0]=q.x; Wf[i*4+1]=q.y; Wf[i*4+2]=q.z; Wf[i*4+3]=q.w;
    }
  }
  float xv[16];
#pragma unroll
  for (int i = 0; i < 4; ++i) {
    const float4 q = *(const float4*)(xr + (i << 2));
    xv[i*4+0]=q.x; xv[i*4+1]=q.y; xv[i*4+2]=q.z; xv[i*4+3]=q.w;
  }
#pragma unroll
  for (int xi = 0; xi < 4; ++xi)
#pragma unroll
    for (int z = 0; z < 4; ++z)
      V[xi*4+z] = fmaf(xv[xi*4+0], Wf[z],
                  fmaf(xv[xi*4+1], Wf[4+z],
                  fmaf(xv[xi*4+2], Wf[8+z],
                       xv[xi*4+3]* Wf[12+z])));
}

// partial segment per (pos, quarter): [0..511] S1 at o*16+p, [512..1023] S2,
// [1024..1055] rs(o). offset = (pos*4+quarter)*1056.
__global__ __launch_bounds__(512, 4) void caps_stats(
    const float* __restrict__ X, const float* __restrict__ A, const float* __restrict__ Wt,
    const float* __restrict__ Bu, const float* __restrict__ Ba,
    const float* __restrict__ prev, float* __restrict__ cur, int it)
{
  __shared__ float xp_s[2*72*16];   // both positions' quarter-patch   9216 B
  __shared__ float a_s[2*72];       // activations                      576 B
  __shared__ float part[8*544];     // per-wave partials, 2-phase     17408 B
  __shared__ float prs[8*32];       // per-wave sum Ra                 1024 B
                                    // total ~28.2 KB -> 4 blocks/CU

  const int t    = threadIdx.x;
  const int o    = t & 31;
  const int ng   = (t >> 5) & 7;    // 0..7
  const int ph   = t >> 8;          // 0/1: position within the pair
  const int wv   = t >> 6;          // 0..7 (waves 0-3 = ph0, 4-7 = ph1)
  const int lane = t & 63;

  const int bid     = blockIdx.x;   // 0..1151
  const int quarter = bid & 3;      // co-resident blocks share quarter
  const int pair    = bid >> 2;     // 0..287
  const int nbase   = quarter * 72;
  const int mypos   = pair*2 + ph;

  // ---- stage both positions' quarter-patches (72 rows each)
  for (int i = t; i < 576; i += 512) {        // 288 float4 chunks per pos
    const int pp  = (i >= 288) ? 1 : 0;
    const int loc = i - pp*288;
    const int r   = loc >> 2, q4 = loc & 3;
    const int pos = pair*2 + pp;
    const int b = pos/144, r_ = pos - b*144, h = r_/12, w = r_ - (r_/12)*12;
    const int n = nbase + r;
    const int kl = n >> 5, c = n & 31;
    const int hy = h + kl/3, wx = w + (kl - (kl/3)*3);
    const float4 v = *(const float4*)(X + ((((b*14+hy)*14+wx) << 9) + (c << 4) + (q4 << 2)));
    *(float4*)(xp_s + pp*1152 + (r << 4) + (q4 << 2)) = v;
  }
  if (t < 144) {
    const int pp  = (t >= 72) ? 1 : 0;
    const int r   = t - pp*72;
    const int pos = pair*2 + pp;
    const int b = pos/144, r_ = pos - b*144, h = r_/12, w = r_ - (r_/12)*12;
    const int n = nbase + r;
    const int kl = n >> 5, c = n & 31;
    const int hy = h + kl/3, wx = w + (kl - (kl/3)*3);
    a_s[pp*72 + r] = A[((b*14+hy)*14+wx)*32 + c];
  }

  // ---- per-thread routing state from prev partials (4 segments, no barriers)
  float mu_r[16], isig_r[16];
  float la_r = 0.f, slog_r = 0.f;
  if (it > 0) {
    float s1[16], s2[16];
    float rsum = EPSV;
#pragma unroll
    for (int p = 0; p < 16; ++p) { s1[p] = 0.f; s2[p] = 0.f; }
#pragma unroll
    for (int q = 0; q < 4; ++q) {
      const float* sg = prev + (mypos*4 + q)*1056;
#pragma unroll
      for (int k = 0; k < 4; ++k) {
        const float4 u = *(const float4*)(sg + (o << 4) + (k << 2));
        s1[k*4+0]+=u.x; s1[k*4+1]+=u.y; s1[k*4+2]+=u.z; s1[k*4+3]+=u.w;
        const float4 v = *(const float4*)(sg + 512 + (o << 4) + (k << 2));
        s2[k*4+0]+=v.x; s2[k*4+1]+=v.y; s2[k*4+2]+=v.z; s2[k*4+3]+=v.w;
      }
      rsum += sg[1024 + o];
    }
    float slog = 0.f;
#pragma unroll
    for (int p = 0; p < 16; ++p) {
      const float mu = s1[p] / rsum;
      float var = s2[p] / rsum - mu*mu;
      var = fmaxf(var, 0.f);
      const float sg2 = var + EPSV;
      mu_r[p]   = mu;
      isig_r[p] = 1.0f / sg2;
      slog     += __logf(sg2);
    }
    const float cost = rsum * (16.0f*Bu[o] + 0.5f*slog);
    const float av = 1.0f / (1.0f + __expf(-(Ba[o] - cost)));   // LAM=1
    la_r   = __logf(av + EPSV);
    slog_r = slog;
  } else {
#pragma unroll
    for (int p = 0; p < 16; ++p) { mu_r[p] = 0.f; isig_r[p] = 0.f; }
  }
  __syncthreads();   // staging visible

  // ---- fused stats pass over this quarter's 72 n's (j=9)
  float S1[16], S2[16];
#pragma unroll
  for (int p = 0; p < 16; ++p) { S1[p] = 0.f; S2[p] = 0.f; }
  float rs = 0.f;

#pragma unroll 1
  for (int j = 0; j < 9; ++j) {
    const int nl = ng + (j << 3);           // local row 0..71
    const int n  = nbase + nl;              // global n: SAME for ph=0/1 -> L1 hit
    float V[16];
    compute_votes(Wt, xp_s + ph*1152 + (nl << 4), n, o, V);

    float ra;
    if (it == 0) {
      ra = a_s[ph*72 + nl] * (1.0f/32.0f);
    } else {
      float q0 = 0.f, q1 = 0.f, q2 = 0.f, q3 = 0.f;
#pragma unroll
      for (int p = 0; p < 4; ++p) {
        float d;
        d = V[p]    - mu_r[p];    q0 = fmaf(d*d, isig_r[p],    q0);
        d = V[p+4]  - mu_r[p+4];  q1 = fmaf(d*d, isig_r[p+4],  q1);
        d = V[p+8]  - mu_r[p+8];  q2 = fmaf(d*d, isig_r[p+8],  q2);
        d = V[p+12] - mu_r[p+12]; q3 = fmaf(d*d, isig_r[p+12], q3);
      }
      const float q = slog_r + ((q0 + q1) + (q2 + q3));
      const float z = la_r - 0.5f*q;
      const float m  = red_max32(z);
      const float ev = __expf(z - m);
      const float s  = red_sum32(ev);
      ra = (ev / s) * a_s[ph*72 + nl];
    }
    rs += ra;
#pragma unroll
    for (int p = 0; p < 16; ++p) {
      const float rv = ra * V[p];
      S1[p] += rv;
      S2[p] = fmaf(rv, V[p], S2[p]);
    }
  }

  // ---- pair-combine the wave's two ng's via lane^32
#pragma unroll
  for (int p = 0; p < 16; ++p) {
    S1[p] += __shfl_xor(S1[p], 32);
    S2[p] += __shfl_xor(S2[p], 32);
  }
  rs += __shfl_xor(rs, 32);

  float* seg0 = cur + ((pair*2 + 0)*4 + quarter)*1056;
  float* seg1 = cur + ((pair*2 + 1)*4 + quarter)*1056;

  // ---- phase A: S1 partials -> global (+rs)
  if (lane < 32) {
    float* p1 = part + wv*544 + o*17;
#pragma unroll
    for (int p = 0; p < 16; ++p) p1[p] = S1[p];
    prs[wv*32 + o] = rs;
  }
  __syncthreads();
  for (int c = t; c < 1024; c += 512) {
    const int pc = c >> 9, idx = c & 511;
    const int pi = idx >> 5, oo = idx & 31;
    float s = 0.f;
#pragma unroll
    for (int g = 0; g < 4; ++g) s += part[(pc*4 + g)*544 + oo*17 + pi];
    (pc ? seg1 : seg0)[(oo << 4) + pi] = s;
  }
  if (t < 64) {
    const int pc = t >> 5, oo = t & 31;
    float r = 0.f;
#pragma unroll
    for (int g = 0; g < 4; ++g) r += prs[(pc*4 + g)*32 + oo];
    (pc ? seg1 : seg0)[1024 + oo] = r;
  }
  __syncthreads();

  // ---- phase B: S2 partials -> global
  if (lane < 32) {
    float* p2 = part + wv*544 + o*17;
#pragma unroll
    for (int p = 0; p < 16; ++p) p2[p] = S2[p];
  }
  __syncthreads();
  for (int c = t; c < 1024; c += 512) {
    const int pc = c >> 9, idx = c & 511;
    const int pi = idx >> 5, oo = idx & 31;
    float s = 0.f;
#pragma unroll
    for (int g = 0; g < 4; ++g) s += part[(pc*4 + g)*544 + oo*17 + pi];
    (pc ? seg1 : seg0)[512 + (oo << 4) + pi] = s;
  }
}

// ---- final: mu/aout from last partials -> Out. One block per position.
__global__ __launch_bounds__(512, 4) void caps_final(
    const float* __restrict__ prev, const float* __restrict__ Bu,
    const float* __restrict__ Ba, float* __restrict__ Out)
{
  __shared__ float lsig_t[512];   // log sig2 at o*16+p
  __shared__ float rs_s[32], aout_s[32];

  const int t   = threadIdx.x;
  const int pos = blockIdx.x;
  const int oo  = t >> 4;

  float s1 = 0.f, s2 = 0.f, rsum = EPSV;
#pragma unroll
  for (int q = 0; q < 4; ++q) {
    const float* sg = prev + (pos*4 + q)*1056;
    s1   += sg[t];
    s2   += sg[512 + t];
    rsum += (t < 32) ? 0.f : 0.f;   // rsum handled below (per-o)
  }
#pragma unroll
  for (int q = 0; q < 4; ++q) rsum += prev[(pos*4 + q)*1056 + 1024 + oo];

  const float mu = s1 / rsum;
  float var = s2 / rsum - mu*mu;
  var = fmaxf(var, 0.f);
  lsig_t[t] = __logf(var + EPSV);
  if ((t & 15) == 0) rs_s[oo] = rsum;
  __syncthreads();
  if (t < 32) {
    float slog = 0.f;
#pragma unroll
    for (int p = 0; p < 16; ++p) slog += lsig_t[(t << 4) + p];
    const float cost = rs_s[t] * (16.0f*Bu[t] + 0.5f*slog);
    aout_s[t] = 1.0f / (1.0f + __expf(-(Ba[t] - cost)));
  }
  __syncthreads();
  Out[pos*512 + t] = mu;          // pose flat index = o*16 + p = t (coalesced)
  if (t < 32) Out[294912 + pos*32 + t] = aout_s[t];
}

extern "C" void kernel_launch(void* const* d_in, const int* in_sizes, int n_in,
                              void* d_out, int out_size, void* d_ws, size_t ws_size,
                              hipStream_t stream) {
  (void)in_sizes; (void)n_in; (void)ws_size; (void)out_size;
  const float* X  = (const float*)d_in[0];
  const float* A  = (const float*)d_in[1];
  const float* Wt = (const float*)d_in[2];
  const float* Bu = (const float*)d_in[3];
  const float* Ba = (const float*)d_in[4];
  float* Out = (float*)d_out;

  float* pa = (float*)d_ws;                 // parity A: 576*4*1056 floats (~9.7MB)
  float* pb = pa + 576*4*1056;              // parity B

  hipLaunchKernelGGL(caps_stats, dim3(1152), dim3(512), 0, stream,
                     X, A, Wt, Bu, Ba, (const float*)nullptr, pa, 0);
  hipLaunchKernelGGL(caps_stats, dim3(1152), dim3(512), 0, stream,
                     X, A, Wt, Bu, Ba, pa, pb, 1);
  hipLaunchKernelGGL(caps_stats, dim3(1152), dim3(512), 0, stream,
                     X, A, Wt, Bu, Ba, pb, pa, 2);
  hipLaunchKernelGGL(caps_final, dim3(576), dim3(512), 0, stream,
                     pa, Bu, Ba, Out);
}

// Round 21
// 180.597 us; speedup vs baseline: 1.1798x; 1.1798x over previous
//
#include <hip/hip_runtime.h>

// ConvCapsMatrix EM routing, MI355X. Inputs FP32, output FP32.
// R21 = R20 grid/j-loop (1152 blocks = (pos-pair, n-quarter), 4 blocks/CU full
// residency, 2-way W-sharing) + R18-style LDS-cooperative state recompute
// (R20's per-thread recompute from global partials caused the 38->67us
// regression: ~512x duplicated log/div work + uncoalesced partial loads,
// FETCH 10->24MB). One cell per thread, coalesced loads, DPP slog reduction.

#define EPSV 1e-8f

template <int CTRL>
__device__ __forceinline__ float dppf(float v) {
  return __int_as_float(__builtin_amdgcn_update_dpp(
      0, __float_as_int(v), CTRL, 0xf, 0xf, true));
}
__device__ __forceinline__ float swz16(float v) {   // lane ^ 16 within 32-groups
  return __int_as_float(__builtin_amdgcn_ds_swizzle(__float_as_int(v), 0x401F));
}
__device__ __forceinline__ float red_max32(float v) {
  v = fmaxf(v, dppf<0xB1>(v));
  v = fmaxf(v, dppf<0x4E>(v));
  v = fmaxf(v, dppf<0x141>(v));
  v = fmaxf(v, dppf<0x140>(v));
  v = fmaxf(v, swz16(v));
  return v;
}
__device__ __forceinline__ float red_sum32(float v) {
  v += dppf<0xB1>(v);
  v += dppf<0x4E>(v);
  v += dppf<0x141>(v);
  v += dppf<0x140>(v);
  v += swz16(v);
  return v;
}
__device__ __forceinline__ float red_sum16(float v) { // over 16-lane groups
  v += dppf<0xB1>(v);
  v += dppf<0x4E>(v);
  v += dppf<0x141>(v);
  v += dppf<0x140>(v);
  return v;
}

__device__ __forceinline__ void compute_votes(const float* __restrict__ Wt,
                                              const float* __restrict__ xr,
                                              int n, int o, float* __restrict__ V)
{
  // W[k,l,c,o,y,z] flat = (n*32+o)*16 + y*4+z ; xr = local pose row (16 f)
  float Wf[16];
  {
    const float* wp = Wt + (((n << 5) + o) << 4);
#pragma unroll
    for (int i = 0; i < 4; ++i) {
      const float4 q = *(const float4*)(wp + (i << 2));
      Wf[i*4+0]=q.x; Wf[i*4+1]=q.y; Wf[i*4+2]=q.z; Wf[i*4+3]=q.w;
    }
  }
  float xv[16];
#pragma unroll
  for (int i = 0; i < 4; ++i) {
    const float4 q = *(const float4*)(xr + (i << 2));
    xv[i*4+0]=q.x; xv[i*4+1]=q.y; xv[i*4+2]=q.z; xv[i*4+3]=q.w;
  }
#pragma unroll
  for (int xi = 0; xi < 4; ++xi)
#pragma unroll
    for (int z = 0; z < 4; ++z)
      V[xi*4+z] = fmaf(xv[xi*4+0], Wf[z],
                  fmaf(xv[xi*4+1], Wf[4+z],
                  fmaf(xv[xi*4+2], Wf[8+z],
                       xv[xi*4+3]* Wf[12+z])));
}

// partial segment per (pos, quarter): [0..511] S1 at o*16+p, [512..1023] S2,
// [1024..1055] rs(o). offset = (pos*4+quarter)*1056.
__global__ __launch_bounds__(512, 4) void caps_stats(
    const float* __restrict__ X, const float* __restrict__ A, const float* __restrict__ Wt,
    const float* __restrict__ Bu, const float* __restrict__ Ba,
    const float* __restrict__ prev, float* __restrict__ cur, int it)
{
  __shared__ float  xp_s[2*72*16];   // both positions' quarter-patch   9216 B
  __shared__ float  a_s[2*72];       // activations                      576 B
  __shared__ float  part[8*544];     // per-wave partials, 2-phase     17408 B
  __shared__ float  prs[8*32];       // per-wave sum Ra                 1024 B
  __shared__ float2 misg_s[2*512];   // {mu,isig}[pp][p*32+o]           8192 B
  __shared__ float  la_s[64];        // log(a_out+eps)[pp*32+o]          256 B
  __shared__ float  slog_s[64];      //                                  256 B
                                     // total ~36.1 KB -> 4 blocks/CU

  const int t    = threadIdx.x;
  const int o    = t & 31;
  const int ng   = (t >> 5) & 7;    // 0..7
  const int ph   = t >> 8;          // 0/1: position within the pair
  const int wv   = t >> 6;          // 0..7
  const int lane = t & 63;

  const int bid     = blockIdx.x;   // 0..1151
  const int quarter = bid & 3;      // co-resident blocks share quarter
  const int pair    = bid >> 2;     // 0..287
  const int nbase   = quarter * 72;

  // ---- stage both positions' quarter-patches (72 rows each)
  for (int i = t; i < 576; i += 512) {        // 288 float4 chunks per pos
    const int pp  = (i >= 288) ? 1 : 0;
    const int loc = i - pp*288;
    const int r   = loc >> 2, q4 = loc & 3;
    const int pos = pair*2 + pp;
    const int b = pos/144, r_ = pos - b*144, h = r_/12, w = r_ - (r_/12)*12;
    const int n = nbase + r;
    const int kl = n >> 5, c = n & 31;
    const int hy = h + kl/3, wx = w + (kl - (kl/3)*3);
    const float4 v = *(const float4*)(X + ((((b*14+hy)*14+wx) << 9) + (c << 4) + (q4 << 2)));
    *(float4*)(xp_s + pp*1152 + (r << 4) + (q4 << 2)) = v;
  }
  if (t < 144) {
    const int pp  = (t >= 72) ? 1 : 0;
    const int r   = t - pp*72;
    const int pos = pair*2 + pp;
    const int b = pos/144, r_ = pos - b*144, h = r_/12, w = r_ - (r_/12)*12;
    const int n = nbase + r;
    const int kl = n >> 5, c = n & 31;
    const int hy = h + kl/3, wx = w + (kl - (kl/3)*3);
    a_s[pp*72 + r] = A[((b*14+hy)*14+wx)*32 + c];
  }

  // ---- cooperative state recompute: one (p,o) cell per thread per position
  if (it > 0) {
    const int oo = t >> 4, pi = t & 15;
#pragma unroll
    for (int pp = 0; pp < 2; ++pp) {
      const float* base = prev + (pair*2 + pp)*4*1056;
      float s1 = 0.f, s2 = 0.f, rsum = EPSV;
#pragma unroll
      for (int q = 0; q < 4; ++q) {
        s1   += base[q*1056 + t];          // coalesced
        s2   += base[q*1056 + 512 + t];    // coalesced
        rsum += base[q*1056 + 1024 + oo];  // broadcast in 16-lane group
      }
      const float mu = s1 / rsum;
      float var = s2 / rsum - mu*mu;
      var = fmaxf(var, 0.f);
      const float sg = var + EPSV;
      const float lg = __logf(sg);
      misg_s[pp*512 + pi*32 + oo] = make_float2(mu, 1.0f / sg);
      const float sl = red_sum16(lg);      // sum over pi within 16-lane group
      if (pi == 0) {
        const float cost = rsum * (16.0f*Bu[oo] + 0.5f*sl);
        const float av = 1.0f / (1.0f + __expf(-(Ba[oo] - cost)));  // LAM=1
        la_s[pp*32 + oo]   = __logf(av + EPSV);
        slog_s[pp*32 + oo] = sl;
      }
    }
  }
  __syncthreads();

  float mu_r[16], isig_r[16];
  float la_r = 0.f, slog_r = 0.f;
  if (it > 0) {
#pragma unroll
    for (int p = 0; p < 16; ++p) {
      const float2 ms = misg_s[ph*512 + p*32 + o];
      mu_r[p]   = ms.x;
      isig_r[p] = ms.y;
    }
    la_r   = la_s[ph*32 + o];
    slog_r = slog_s[ph*32 + o];
  } else {
#pragma unroll
    for (int p = 0; p < 16; ++p) { mu_r[p] = 0.f; isig_r[p] = 0.f; }
  }

  // ---- fused stats pass over this quarter's 72 n's (j=9, W shared ph0/ph1)
  float S1[16], S2[16];
#pragma unroll
  for (int p = 0; p < 16; ++p) { S1[p] = 0.f; S2[p] = 0.f; }
  float rs = 0.f;

#pragma unroll 1
  for (int j = 0; j < 9; ++j) {
    const int nl = ng + (j << 3);           // local row 0..71
    const int n  = nbase + nl;              // same n for ph=0/1 -> L1 hit
    float V[16];
    compute_votes(Wt, xp_s + ph*1152 + (nl << 4), n, o, V);

    float ra;
    if (it == 0) {
      ra = a_s[ph*72 + nl] * (1.0f/32.0f);
    } else {
      float q0 = 0.f, q1 = 0.f, q2 = 0.f, q3 = 0.f;
#pragma unroll
      for (int p = 0; p < 4; ++p) {
        float d;
        d = V[p]    - mu_r[p];    q0 = fmaf(d*d, isig_r[p],    q0);
        d = V[p+4]  - mu_r[p+4];  q1 = fmaf(d*d, isig_r[p+4],  q1);
        d = V[p+8]  - mu_r[p+8];  q2 = fmaf(d*d, isig_r[p+8],  q2);
        d = V[p+12] - mu_r[p+12]; q3 = fmaf(d*d, isig_r[p+12], q3);
      }
      const float q = slog_r + ((q0 + q1) + (q2 + q3));
      const float z = la_r - 0.5f*q;
      const float m  = red_max32(z);
      const float ev = __expf(z - m);
      const float s  = red_sum32(ev);
      ra = (ev / s) * a_s[ph*72 + nl];
    }
    rs += ra;
#pragma unroll
    for (int p = 0; p < 16; ++p) {
      const float rv = ra * V[p];
      S1[p] += rv;
      S2[p] = fmaf(rv, V[p], S2[p]);
    }
  }

  // ---- pair-combine the wave's two ng's via lane^32
#pragma unroll
  for (int p = 0; p < 16; ++p) {
    S1[p] += __shfl_xor(S1[p], 32);
    S2[p] += __shfl_xor(S2[p], 32);
  }
  rs += __shfl_xor(rs, 32);

  float* seg0 = cur + ((pair*2 + 0)*4 + quarter)*1056;
  float* seg1 = cur + ((pair*2 + 1)*4 + quarter)*1056;

  // ---- phase A: S1 partials -> global (+rs)
  if (lane < 32) {
    float* p1 = part + wv*544 + o*17;
#pragma unroll
    for (int p = 0; p < 16; ++p) p1[p] = S1[p];
    prs[wv*32 + o] = rs;
  }
  __syncthreads();
  for (int c = t; c < 1024; c += 512) {
    const int pc = c >> 9, idx = c & 511;
    const int pi = idx >> 5, oo = idx & 31;
    float s = 0.f;
#pragma unroll
    for (int g = 0; g < 4; ++g) s += part[(pc*4 + g)*544 + oo*17 + pi];
    (pc ? seg1 : seg0)[(oo << 4) + pi] = s;
  }
  if (t < 64) {
    const int pc = t >> 5, oo = t & 31;
    float r = 0.f;
#pragma unroll
    for (int g = 0; g < 4; ++g) r += prs[(pc*4 + g)*32 + oo];
    (pc ? seg1 : seg0)[1024 + oo] = r;
  }
  __syncthreads();

  // ---- phase B: S2 partials -> global
  if (lane < 32) {
    float* p2 = part + wv*544 + o*17;
#pragma unroll
    for (int p = 0; p < 16; ++p) p2[p] = S2[p];
  }
  __syncthreads();
  for (int c = t; c < 1024; c += 512) {
    const int pc = c >> 9, idx = c & 511;
    const int pi = idx >> 5, oo = idx & 31;
    float s = 0.f;
#pragma unroll
    for (int g = 0; g < 4; ++g) s += part[(pc*4 + g)*544 + oo*17 + pi];
    (pc ? seg1 : seg0)[512 + (oo << 4) + pi] = s;
  }
}

// ---- final: mu/aout from last partials -> Out. One block per position.
__global__ __launch_bounds__(512, 4) void caps_final(
    const float* __restrict__ prev, const float* __restrict__ Bu,
    const float* __restrict__ Ba, float* __restrict__ Out)
{
  __shared__ float lsig_t[512];   // log sig2 at o*16+p
  __shared__ float rs_s[32], aout_s[32];

  const int t   = threadIdx.x;
  const int pos = blockIdx.x;
  const int oo  = t >> 4;

  float s1 = 0.f, s2 = 0.f, rsum = EPSV;
#pragma unroll
  for (int q = 0; q < 4; ++q) {
    const float* sg = prev + (pos*4 + q)*1056;
    s1   += sg[t];
    s2   += sg[512 + t];
    rsum += sg[1024 + oo];
  }

  const float mu = s1 / rsum;
  float var = s2 / rsum - mu*mu;
  var = fmaxf(var, 0.f);
  lsig_t[t] = __logf(var + EPSV);
  if ((t & 15) == 0) rs_s[oo] = rsum;
  __syncthreads();
  if (t < 32) {
    float slog = 0.f;
#pragma unroll
    for (int p = 0; p < 16; ++p) slog += lsig_t[(t << 4) + p];
    const float cost = rs_s[t] * (16.0f*Bu[t] + 0.5f*slog);
    aout_s[t] = 1.0f / (1.0f + __expf(-(Ba[t] - cost)));
  }
  __syncthreads();
  Out[pos*512 + t] = mu;          // pose flat index = o*16 + p = t (coalesced)
  if (t < 32) Out[294912 + pos*32 + t] = aout_s[t];
}

extern "C" void kernel_launch(void* const* d_in, const int* in_sizes, int n_in,
                              void* d_out, int out_size, void* d_ws, size_t ws_size,
                              hipStream_t stream) {
  (void)in_sizes; (void)n_in; (void)ws_size; (void)out_size;
  const float* X  = (const float*)d_in[0];
  const float* A  = (const float*)d_in[1];
  const float* Wt = (const float*)d_in[2];
  const float* Bu = (const float*)d_in[3];
  const float* Ba = (const float*)d_in[4];
  float* Out = (float*)d_out;

  float* pa = (float*)d_ws;                 // parity A: 576*4*1056 floats (~9.7MB)
  float* pb = pa + 576*4*1056;              // parity B

  hipLaunchKernelGGL(caps_stats, dim3(1152), dim3(512), 0, stream,
                     X, A, Wt, Bu, Ba, (const float*)nullptr, pa, 0);
  hipLaunchKernelGGL(caps_stats, dim3(1152), dim3(512), 0, stream,
                     X, A, Wt, Bu, Ba, pa, pb, 1);
  hipLaunchKernelGGL(caps_stats, dim3(1152), dim3(512), 0, stream,
                     X, A, Wt, Bu, Ba, pb, pa, 2);
  hipLaunchKernelGGL(caps_final, dim3(576), dim3(512), 0, stream,
                     pa, Bu, Ba, Out);
}

// Round 22
// 174.907 us; speedup vs baseline: 1.2182x; 1.0325x over previous
//
#include <hip/hip_runtime.h>

// ConvCapsMatrix EM routing, MI355X. Inputs FP32, output FP32.
// R22: wave = 32 o x 2 POSITIONS, same n per wave -> the two ph-halves request
// identical W rows and the coalescer merges them: 2KB instead of 4KB of W per
// wave-j (the L1 W path ~= VALU was the R10-R21 plateau). Register cost zero:
// each thread keeps one position's state (R18 live set). Softmax over o = the
// 32-lane DPP reductions (ph halves are independent 32-groups natively).
// Block = (pair, half): 576 x 512thr, 8 waves, j=18; partials per (pos,half)
// as R18; 4-phase ph-split reduction reusing one slab. LDS ~47KB -> 3/CU.

#define EPSV 1e-8f

template <int CTRL>
__device__ __forceinline__ float dppf(float v) {
  return __int_as_float(__builtin_amdgcn_update_dpp(
      0, __float_as_int(v), CTRL, 0xf, 0xf, true));
}
__device__ __forceinline__ float swz16(float v) {   // lane ^ 16 within 32-groups
  return __int_as_float(__builtin_amdgcn_ds_swizzle(__float_as_int(v), 0x401F));
}
__device__ __forceinline__ float red_max32(float v) {
  v = fmaxf(v, dppf<0xB1>(v));
  v = fmaxf(v, dppf<0x4E>(v));
  v = fmaxf(v, dppf<0x141>(v));
  v = fmaxf(v, dppf<0x140>(v));
  v = fmaxf(v, swz16(v));
  return v;
}
__device__ __forceinline__ float red_sum32(float v) {
  v += dppf<0xB1>(v);
  v += dppf<0x4E>(v);
  v += dppf<0x141>(v);
  v += dppf<0x140>(v);
  v += swz16(v);
  return v;
}
__device__ __forceinline__ float red_sum16(float v) { // within 16-lane groups
  v += dppf<0xB1>(v);
  v += dppf<0x4E>(v);
  v += dppf<0x141>(v);
  v += dppf<0x140>(v);
  return v;
}

__device__ __forceinline__ void compute_votes(const float* __restrict__ Wt,
                                              const float* __restrict__ xr,
                                              int n, int o, float* __restrict__ V)
{
  // W[k,l,c,o,y,z] flat = (n*32+o)*16 + y*4+z ; xr = local pose row (16 f)
  float Wf[16];
  {
    const float* wp = Wt + (((n << 5) + o) << 4);
#pragma unroll
    for (int i = 0; i < 4; ++i) {
      const float4 q = *(const float4*)(wp + (i << 2));
      Wf[i*4+0]=q.x; Wf[i*4+1]=q.y; Wf[i*4+2]=q.z; Wf[i*4+3]=q.w;
    }
  }
  float xv[16];
#pragma unroll
  for (int i = 0; i < 4; ++i) {
    const float4 q = *(const float4*)(xr + (i << 2));
    xv[i*4+0]=q.x; xv[i*4+1]=q.y; xv[i*4+2]=q.z; xv[i*4+3]=q.w;
  }
#pragma unroll
  for (int xi = 0; xi < 4; ++xi)
#pragma unroll
    for (int z = 0; z < 4; ++z)
      V[xi*4+z] = fmaf(xv[xi*4+0], Wf[z],
                  fmaf(xv[xi*4+1], Wf[4+z],
                  fmaf(xv[xi*4+2], Wf[8+z],
                       xv[xi*4+3]* Wf[12+z])));
}

// partial segment per (pos, half): [0..511] S1 at o*16+p, [512..1023] S2,
// [1024..1055] rs(o). offset = (pos*2+half)*1056.
__global__ __launch_bounds__(512, 4) void caps_stats(
    const float* __restrict__ X, const float* __restrict__ A, const float* __restrict__ Wt,
    const float* __restrict__ Bu, const float* __restrict__ Ba,
    const float* __restrict__ prev, float* __restrict__ cur, int it)
{
  __shared__ float  xp_s[2*144*16];  // both positions' half-patch     18432 B
  __shared__ float  a_s[2*144];      // activations                     1152 B
  __shared__ float  part[8*544];     // per-wave slab, 4-phase reuse   17408 B
  __shared__ float  prs[8*32];       // per-wave rs                     1024 B
  __shared__ float2 misg_s[2*512];   // {mu,isig}[pp][p*32+o]           8192 B
  __shared__ float  la_s[64];        // [pp*32+o]                        256 B
  __shared__ float  slog_s[64];      //                                  256 B
                                     // total ~46.7 KB -> 3 blocks/CU

  const int t    = threadIdx.x;
  const int lane = t & 63;
  const int o    = lane & 31;
  const int ph   = lane >> 5;       // position within the pair (lane geometry!)
  const int wv   = t >> 6;          // 0..7

  const int bid   = blockIdx.x;     // 0..575
  const int pair  = bid >> 1;       // 0..287
  const int half  = bid & 1;
  const int nbase = half * 144;

  // ---- stage both positions' half-patches (144 rows each)
  for (int i = t; i < 1152; i += 512) {       // float4 chunks
    const int pp  = (i >= 576) ? 1 : 0;
    const int loc = i - pp*576;
    const int r   = loc >> 2, q4 = loc & 3;
    const int pos = pair*2 + pp;
    const int b = pos/144, r_ = pos - b*144, h = r_/12, w = r_ - (r_/12)*12;
    const int n = nbase + r;
    const int kl = n >> 5, c = n & 31;
    const int hy = h + kl/3, wx = w + (kl - (kl/3)*3);
    const float4 v = *(const float4*)(X + ((((b*14+hy)*14+wx) << 9) + (c << 4) + (q4 << 2)));
    *(float4*)(xp_s + pp*2304 + (r << 4) + (q4 << 2)) = v;
  }
  if (t < 288) {
    const int pp  = (t >= 144) ? 1 : 0;
    const int r   = t - pp*144;
    const int pos = pair*2 + pp;
    const int b = pos/144, r_ = pos - b*144, h = r_/12, w = r_ - (r_/12)*12;
    const int n = nbase + r;
    const int kl = n >> 5, c = n & 31;
    const int hy = h + kl/3, wx = w + (kl - (kl/3)*3);
    a_s[pp*144 + r] = A[((b*14+hy)*14+wx)*32 + c];
  }

  // ---- cooperative state recompute: one (p,o) cell per thread per position
  if (it > 0) {
    const int oo = t >> 4, pi = t & 15;
#pragma unroll
    for (int pp = 0; pp < 2; ++pp) {
      const float* h0 = prev + ((pair*2 + pp)*2 + 0)*1056;
      const float* h1 = prev + ((pair*2 + pp)*2 + 1)*1056;
      const float s1   = h0[t]       + h1[t];         // coalesced (o*16+p = t)
      const float s2   = h0[512 + t] + h1[512 + t];
      const float rsum = h0[1024+oo] + h1[1024+oo] + EPSV;
      const float mu = s1 / rsum;
      float var = s2 / rsum - mu*mu;
      var = fmaxf(var, 0.f);
      const float sg = var + EPSV;
      const float lg = __logf(sg);
      misg_s[pp*512 + pi*32 + oo] = make_float2(mu, 1.0f / sg);
      const float sl = red_sum16(lg);      // sum over pi within 16-lane group
      if (pi == 0) {
        const float cost = rsum * (16.0f*Bu[oo] + 0.5f*sl);
        const float av = 1.0f / (1.0f + __expf(-(Ba[oo] - cost)));  // LAM=1
        la_s[pp*32 + oo]   = __logf(av + EPSV);
        slog_s[pp*32 + oo] = sl;
      }
    }
  }
  __syncthreads();

  float mu_r[16], isig_r[16];
  float la_r = 0.f, slog_r = 0.f;
  if (it > 0) {
#pragma unroll
    for (int p = 0; p < 16; ++p) {
      const float2 ms = misg_s[ph*512 + p*32 + o];
      mu_r[p]   = ms.x;
      isig_r[p] = ms.y;
    }
    la_r   = la_s[ph*32 + o];
    slog_r = slog_s[ph*32 + o];
  } else {
#pragma unroll
    for (int p = 0; p < 16; ++p) { mu_r[p] = 0.f; isig_r[p] = 0.f; }
  }

  // ---- fused stats pass: wave wv handles n = nbase + wv + j*8, j<18.
  // All 64 lanes share one n -> ph0/ph1 lanes request identical W rows.
  float S1[16], S2[16];
#pragma unroll
  for (int p = 0; p < 16; ++p) { S1[p] = 0.f; S2[p] = 0.f; }
  float rs = 0.f;

#pragma unroll 1
  for (int j = 0; j < 18; ++j) {
    const int nl = wv + (j << 3);           // local row 0..143
    const int n  = nbase + nl;
    float V[16];
    compute_votes(Wt, xp_s + ph*2304 + (nl << 4), n, o, V);

    float ra;
    if (it == 0) {
      ra = a_s[ph*144 + nl] * (1.0f/32.0f);
    } else {
      float q0 = 0.f, q1 = 0.f, q2 = 0.f, q3 = 0.f;
#pragma unroll
      for (int p = 0; p < 4; ++p) {
        float d;
        d = V[p]    - mu_r[p];    q0 = fmaf(d*d, isig_r[p],    q0);
        d = V[p+4]  - mu_r[p+4];  q1 = fmaf(d*d, isig_r[p+4],  q1);
        d = V[p+8]  - mu_r[p+8];  q2 = fmaf(d*d, isig_r[p+8],  q2);
        d = V[p+12] - mu_r[p+12]; q3 = fmaf(d*d, isig_r[p+12], q3);
      }
      const float q = slog_r + ((q0 + q1) + (q2 + q3));
      const float z = la_r - 0.5f*q;
      const float m  = red_max32(z);        // within each ph's 32 lanes
      const float ev = __expf(z - m);
      const float s  = red_sum32(ev);
      ra = (ev / s) * a_s[ph*144 + nl];
    }
    rs += ra;
#pragma unroll
    for (int p = 0; p < 16; ++p) {
      const float rv = ra * V[p];
      S1[p] += rv;
      S2[p] = fmaf(rv, V[p], S2[p]);
    }
  }

  float* seg0 = cur + ((pair*2 + 0)*2 + half)*1056;
  float* seg1 = cur + ((pair*2 + 1)*2 + half)*1056;

  // ---- 4-phase ph-split reduction reusing one slab
#pragma unroll
  for (int phase = 0; phase < 4; ++phase) {
    const int  wp  = phase & 1;             // which position's lanes write
    const bool s2p = phase >= 2;            // S1 phases first, then S2
    if (ph == wp) {
      float* pw = part + wv*544 + o*17;
      if (!s2p) {
#pragma unroll
        for (int p = 0; p < 16; ++p) pw[p] = S1[p];
        prs[wv*32 + o] = rs;
      } else {
#pragma unroll
        for (int p = 0; p < 16; ++p) pw[p] = S2[p];
      }
    }
    __syncthreads();
    {
      const int oo = t >> 4, pi = t & 15;
      float s = 0.f;
#pragma unroll
      for (int g = 0; g < 8; ++g) s += part[g*544 + oo*17 + pi];
      float* seg = wp ? seg1 : seg0;
      seg[(s2p ? 512 : 0) + t] = s;         // t = oo*16+pi (coalesced)
      if (!s2p && t < 32) {
        float r = 0.f;
#pragma unroll
        for (int g = 0; g < 8; ++g) r += prs[(g << 5) + t];
        seg[1024 + t] = r;
      }
    }
    __syncthreads();
  }
}

// ---- final: mu/aout from last partials -> Out. One block per position.
__global__ __launch_bounds__(512, 4) void caps_final(
    const float* __restrict__ prev, const float* __restrict__ Bu,
    const float* __restrict__ Ba, float* __restrict__ Out)
{
  __shared__ float lsig_t[512];   // log sig2 at o*16+p
  __shared__ float rs_s[32], aout_s[32];

  const int t   = threadIdx.x;
  const int pos = blockIdx.x;
  const int oo  = t >> 4;
  const float* h0 = prev + (pos*2 + 0)*1056;
  const float* h1 = prev + (pos*2 + 1)*1056;

  const float rsum = h0[1024+oo] + h1[1024+oo] + EPSV;
  const float s1 = h0[t]     + h1[t];
  const float s2 = h0[512+t] + h1[512+t];
  const float mu = s1 / rsum;
  float var = s2 / rsum - mu*mu;
  var = fmaxf(var, 0.f);
  lsig_t[t] = __logf(var + EPSV);
  if ((t & 15) == 0) rs_s[oo] = rsum;
  __syncthreads();
  if (t < 32) {
    float slog = 0.f;
#pragma unroll
    for (int p = 0; p < 16; ++p) slog += lsig_t[(t << 4) + p];
    const float cost = rs_s[t] * (16.0f*Bu[t] + 0.5f*slog);
    aout_s[t] = 1.0f / (1.0f + __expf(-(Ba[t] - cost)));
  }
  __syncthreads();
  Out[pos*512 + t] = mu;          // pose flat index = o*16 + p = t (coalesced)
  if (t < 32) Out[294912 + pos*32 + t] = aout_s[t];
}

extern "C" void kernel_launch(void* const* d_in, const int* in_sizes, int n_in,
                              void* d_out, int out_size, void* d_ws, size_t ws_size,
                              hipStream_t stream) {
  (void)in_sizes; (void)n_in; (void)ws_size; (void)out_size;
  const float* X  = (const float*)d_in[0];
  const float* A  = (const float*)d_in[1];
  const float* Wt = (const float*)d_in[2];
  const float* Bu = (const float*)d_in[3];
  const float* Ba = (const float*)d_in[4];
  float* Out = (float*)d_out;

  float* pa = (float*)d_ws;                 // parity A: 1152*1056 floats
  float* pb = pa + 1152*1056;               // parity B (~9.7MB total)

  hipLaunchKernelGGL(caps_stats, dim3(576), dim3(512), 0, stream,
                     X, A, Wt, Bu, Ba, (const float*)nullptr, pa, 0);
  hipLaunchKernelGGL(caps_stats, dim3(576), dim3(512), 0, stream,
                     X, A, Wt, Bu, Ba, pa, pb, 1);
  hipLaunchKernelGGL(caps_stats, dim3(576), dim3(512), 0, stream,
                     X, A, Wt, Bu, Ba, pb, pa, 2);
  hipLaunchKernelGGL(caps_final, dim3(576), dim3(512), 0, stream,
                     pa, Bu, Ba, Out);
}